// Round 1
// baseline (138.196 us; speedup 1.0000x reference)
//
#include <hip/hip_runtime.h>

#define BATCH   8
#define SHAPE_N 8192
#define SKEL_M  2048
#define SSTRIDE 6   // shape_xyz innermost dim; use first 3

// ---------------------------------------------------------------------------
// Kernel 1: for each shape point, min over 2048 skel pts (LDS broadcast),
// sqrt(min d2), block-reduce sum, atomicAdd scaled partial into out.
// grid = 8 batches * 32 chunks = 256 blocks, 256 thr (1 thread = 1 point)
// ---------------------------------------------------------------------------
__global__ __launch_bounds__(256) void cd_shape_to_skel(
    const float* __restrict__ shape, const float* __restrict__ skel,
    float* __restrict__ out)
{
    __shared__ float4 s_skel[SKEL_M];   // 32 KB, padded for ds_read_b128
    __shared__ float  s_wsum[4];

    const int b     = blockIdx.x >> 5;
    const int chunk = blockIdx.x & 31;
    const int tid   = threadIdx.x;

    const float* skel_b = skel + (size_t)b * SKEL_M * 3;
    for (int m = tid; m < SKEL_M; m += 256) {
        s_skel[m] = make_float4(skel_b[3 * m], skel_b[3 * m + 1], skel_b[3 * m + 2], 0.f);
    }
    __syncthreads();

    const int n = chunk * 256 + tid;
    const float* p = shape + (size_t)(b * SHAPE_N + n) * SSTRIDE;
    const float px = p[0], py = p[1], pz = p[2];

    float m0 = 3.4e38f, m1 = 3.4e38f, m2 = 3.4e38f, m3 = 3.4e38f;
    for (int m = 0; m < SKEL_M; m += 4) {
        float4 s0 = s_skel[m + 0];
        float4 s1 = s_skel[m + 1];
        float4 s2 = s_skel[m + 2];
        float4 s3 = s_skel[m + 3];
        float dx, dy, dz, d2;
        dx = px - s0.x; dy = py - s0.y; dz = pz - s0.z;
        d2 = dx * dx + dy * dy + dz * dz; m0 = fminf(m0, d2);
        dx = px - s1.x; dy = py - s1.y; dz = pz - s1.z;
        d2 = dx * dx + dy * dy + dz * dz; m1 = fminf(m1, d2);
        dx = px - s2.x; dy = py - s2.y; dz = pz - s2.z;
        d2 = dx * dx + dy * dy + dz * dz; m2 = fminf(m2, d2);
        dx = px - s3.x; dy = py - s3.y; dz = pz - s3.z;
        d2 = dx * dx + dy * dy + dz * dz; m3 = fminf(m3, d2);
    }
    float d = sqrtf(fminf(fminf(m0, m1), fminf(m2, m3)));

    // wave64 shuffle reduce, then cross-wave via LDS
    for (int off = 32; off; off >>= 1) d += __shfl_down(d, off, 64);
    const int lane = tid & 63, wave = tid >> 6;
    if (lane == 0) s_wsum[wave] = d;
    __syncthreads();
    if (tid == 0) {
        float s = s_wsum[0] + s_wsum[1] + s_wsum[2] + s_wsum[3];
        atomicAdd(out, s * 1e-4f);
    }
}

// ---------------------------------------------------------------------------
// Kernel 2: skel->shape direction. Each thread owns 8 skel pts (registers),
// each block scans a 256-point chunk of shape (LDS), partial mins combined
// across the 32 chunks via atomicMin on uint-bits of nonnegative d2.
// grid = 8 batches * 32 splits = 256 blocks, 256 thr
// ---------------------------------------------------------------------------
__global__ __launch_bounds__(256) void cd_skel_to_shape(
    const float* __restrict__ shape, const float* __restrict__ skel,
    unsigned int* __restrict__ ws)
{
    __shared__ float4 s_pts[256];

    const int b     = blockIdx.x >> 5;
    const int split = blockIdx.x & 31;
    const int tid   = threadIdx.x;

    const int n = split * 256 + tid;
    const float* p = shape + (size_t)(b * SHAPE_N + n) * SSTRIDE;
    s_pts[tid] = make_float4(p[0], p[1], p[2], 0.f);

    float sx[8], sy[8], sz[8], dmin[8];
    const float* skel_b = skel + (size_t)b * SKEL_M * 3;
#pragma unroll
    for (int j = 0; j < 8; ++j) {
        const int m = j * 256 + tid;
        sx[j] = skel_b[3 * m];
        sy[j] = skel_b[3 * m + 1];
        sz[j] = skel_b[3 * m + 2];
        dmin[j] = 3.4e38f;
    }
    __syncthreads();

    for (int i = 0; i < 256; ++i) {
        float4 q = s_pts[i];
#pragma unroll
        for (int j = 0; j < 8; ++j) {
            float dx = q.x - sx[j], dy = q.y - sy[j], dz = q.z - sz[j];
            float d2 = dx * dx + dy * dy + dz * dz;
            dmin[j] = fminf(dmin[j], d2);
        }
    }
#pragma unroll
    for (int j = 0; j < 8; ++j) {
        const int m = j * 256 + tid;
        atomicMin(&ws[b * SKEL_M + m], __float_as_uint(dmin[j]));
    }
}

// ---------------------------------------------------------------------------
// Kernel 3: sqrt + sum the 16384 skel-side mins, atomicAdd into out.
// grid = 64 blocks, 256 thr
// ---------------------------------------------------------------------------
__global__ __launch_bounds__(256) void cd_finalize(
    const unsigned int* __restrict__ ws, float* __restrict__ out)
{
    __shared__ float s_wsum[4];
    const int idx = blockIdx.x * 256 + threadIdx.x;
    float d = sqrtf(__uint_as_float(ws[idx]));
    for (int off = 32; off; off >>= 1) d += __shfl_down(d, off, 64);
    const int lane = threadIdx.x & 63, wave = threadIdx.x >> 6;
    if (lane == 0) s_wsum[wave] = d;
    __syncthreads();
    if (threadIdx.x == 0) {
        float s = s_wsum[0] + s_wsum[1] + s_wsum[2] + s_wsum[3];
        atomicAdd(out, s * 1e-4f);
    }
}

extern "C" void kernel_launch(void* const* d_in, const int* in_sizes, int n_in,
                              void* d_out, int out_size, void* d_ws, size_t ws_size,
                              hipStream_t stream) {
    const float* shape = (const float*)d_in[0];   // (8, 8192, 6)
    const float* skel  = (const float*)d_in[1];   // (8, 2048, 3)
    float* out         = (float*)d_out;           // scalar
    unsigned int* ws   = (unsigned int*)d_ws;     // 16384 uints = 64 KB

    hipMemsetAsync(out, 0, sizeof(float), stream);
    hipMemsetAsync(ws, 0xFF, (size_t)BATCH * SKEL_M * sizeof(unsigned int), stream);

    cd_shape_to_skel<<<256, 256, 0, stream>>>(shape, skel, out);
    cd_skel_to_shape<<<256, 256, 0, stream>>>(shape, skel, ws);
    cd_finalize<<<64, 256, 0, stream>>>(ws, out);
}

// Round 2
// 110.137 us; speedup vs baseline: 1.2548x; 1.2548x over previous
//
#include <hip/hip_runtime.h>

#define BATCH   8
#define SHAPE_N 8192
#define SKEL_M  2048

// ---------------------------------------------------------------------------
// Generic min-distance kernel. Each thread owns 4 A-points in registers;
// each block scans one 256-point chunk of B (staged in LDS as float4).
// Partial mins combined across B-chunks via atomicMin on uint bits of d^2
// (nonnegative floats: IEEE bit order == numeric order).
// grid: x = NB/256 (B chunks), y = NA/1024 (A blocks), z = batch. 256 thr.
// Geometry both directions: 512 blocks = 2 blocks/CU = 2 waves/SIMD.
// ---------------------------------------------------------------------------
template <int STRIDE_A, int STRIDE_B, int NA, int NB>
__global__ __launch_bounds__(256) void cd_min_kernel(
    const float* __restrict__ A, const float* __restrict__ B,
    unsigned int* __restrict__ ws)
{
    __shared__ float4 sB[256];

    const int b   = blockIdx.z;
    const int tid = threadIdx.x;

    // stage B chunk
    {
        const float* q = B + ((size_t)b * NB + blockIdx.x * 256 + tid) * STRIDE_B;
        sB[tid] = make_float4(q[0], q[1], q[2], 0.f);
    }

    // own 4 A points
    const int a0 = blockIdx.y * 1024;
    const float* Ab = A + (size_t)b * NA * STRIDE_A;
    float ax[4], ay[4], az[4], dmin[4];
#pragma unroll
    for (int k = 0; k < 4; ++k) {
        const float* p = Ab + (size_t)(a0 + k * 256 + tid) * STRIDE_A;
        ax[k] = p[0]; ay[k] = p[1]; az[k] = p[2];
        dmin[k] = 3.4e38f;
    }
    __syncthreads();

#pragma unroll 4
    for (int i = 0; i < 256; ++i) {
        float4 q = sB[i];
#pragma unroll
        for (int k = 0; k < 4; ++k) {
            float dx = ax[k] - q.x, dy = ay[k] - q.y, dz = az[k] - q.z;
            float d2 = dx * dx + dy * dy + dz * dz;
            dmin[k] = fminf(dmin[k], d2);
        }
    }

    unsigned int* wsb = ws + (size_t)b * NA;
#pragma unroll
    for (int k = 0; k < 4; ++k)
        atomicMin(&wsb[a0 + k * 256 + tid], __float_as_uint(dmin[k]));
}

// ---------------------------------------------------------------------------
// Finalize: sqrt + sum all 81920 per-point mins, scale, atomicAdd into out.
// grid = 320 blocks x 256 thr.
// ---------------------------------------------------------------------------
__global__ __launch_bounds__(256) void cd_finalize(
    const unsigned int* __restrict__ ws, float* __restrict__ out)
{
    __shared__ float s_wsum[4];
    const int idx = blockIdx.x * 256 + threadIdx.x;
    float d = sqrtf(__uint_as_float(ws[idx]));
    for (int off = 32; off; off >>= 1) d += __shfl_down(d, off, 64);
    const int lane = threadIdx.x & 63, wave = threadIdx.x >> 6;
    if (lane == 0) s_wsum[wave] = d;
    __syncthreads();
    if (threadIdx.x == 0) {
        float s = s_wsum[0] + s_wsum[1] + s_wsum[2] + s_wsum[3];
        atomicAdd(out, s * 1e-4f);
    }
}

extern "C" void kernel_launch(void* const* d_in, const int* in_sizes, int n_in,
                              void* d_out, int out_size, void* d_ws, size_t ws_size,
                              hipStream_t stream) {
    const float* shape = (const float*)d_in[0];   // (8, 8192, 6) — use first 3
    const float* skel  = (const float*)d_in[1];   // (8, 2048, 3)
    float* out         = (float*)d_out;           // scalar
    unsigned int* ws   = (unsigned int*)d_ws;     // 81920 uints = 320 KB

    const size_t n_ws = (size_t)BATCH * (SHAPE_N + SKEL_M);
    hipMemsetAsync(out, 0, sizeof(float), stream);
    hipMemsetAsync(ws, 0xFF, n_ws * sizeof(unsigned int), stream);

    // dir 1: A = shape (65536 pts), B = skel.  grid (8, 8, 8) = 512 blocks
    cd_min_kernel<6, 3, SHAPE_N, SKEL_M>
        <<<dim3(SKEL_M / 256, SHAPE_N / 1024, BATCH), 256, 0, stream>>>(
            shape, skel, ws);

    // dir 2: A = skel (16384 pts), B = shape. grid (32, 2, 8) = 512 blocks
    cd_min_kernel<3, 6, SKEL_M, SHAPE_N>
        <<<dim3(SHAPE_N / 256, SKEL_M / 1024, BATCH), 256, 0, stream>>>(
            skel, shape, ws + (size_t)BATCH * SHAPE_N);

    cd_finalize<<<(BATCH * (SHAPE_N + SKEL_M)) / 256, 256, 0, stream>>>(ws, out);
}